// Round 2
// baseline (2980.959 us; speedup 1.0000x reference)
//
#include <hip/hip_runtime.h>

typedef __bf16 bf16x8 __attribute__((ext_vector_type(8)));
typedef __bf16 bf16x4 __attribute__((ext_vector_type(4)));
typedef float  f32x4  __attribute__((ext_vector_type(4)));

#define N_NODES  50000
#define N_EDGES  500000
#define N_GRAPHS 1024
#define NF       128
#define IN_DIM   92
#define N_LAYERS 5
#define SPAN_CAP 64

__device__ __forceinline__ float sigmoidf_(float x) { return 1.0f / (1.0f + __expf(-x)); }
__device__ __forceinline__ float softplusf_(float x) {
    // max(x,0) + log(1+exp(-|x|)) with fast log; rel err ~1e-7, fine at 0.5% tol
    return fmaxf(x, 0.0f) + __logf(1.0f + __expf(-fabsf(x)));
}
__device__ __forceinline__ float siluf_(float x) { return x * sigmoidf_(x); }

// ---------------------------------------------------------------------------
// Weight prep: Wg/Wc fp32 [L][384][128] -> bf16 B-fragment layout with baked
// LDS swizzle (granule = n*4 + ((sub+(n>>1))&3) within each 4096-elem slice).
// ---------------------------------------------------------------------------
__global__ void __launch_bounds__(256) k_prep_w(const float* __restrict__ Wg,
                                                const float* __restrict__ Wc,
                                                __bf16* __restrict__ Wt) {
    int t = blockIdx.x * 256 + threadIdx.x;
    if (t >= N_LAYERS * 2 * 12 * 128 * 32) return;
    int jj = t & 31;
    int n  = (t >> 5) & 127;
    int s  = (t >> 12) % 12;
    int lg = t / (12 * 4096);
    int l = lg >> 1, g = lg & 1;
    const float* W = g ? Wc : Wg;
    float v = W[l * 384 * 128 + (s * 32 + jj) * 128 + n];
    int sub = jj >> 3, j = jj & 7;
    int gran = n * 4 + ((sub + (n >> 1)) & 3);
    Wt[(size_t)lg * 49152 + (size_t)s * 4096 + gran * 8 + j] = (__bf16)v;
}

// ---------------------------------------------------------------------------
// CSR build: degree histogram -> exclusive scan -> scatter permutation
// ---------------------------------------------------------------------------
__global__ void __launch_bounds__(256) k_deg(const int* __restrict__ dstI,
                                             int* __restrict__ deg) {
    int e = blockIdx.x * 256 + threadIdx.x;
    if (e < N_EDGES) atomicAdd(&deg[dstI[e]], 1);
}

__global__ void __launch_bounds__(1024) k_scan(const int* __restrict__ deg,
                                               int* __restrict__ cursor) {
    __shared__ int ps[1024];
    int t = threadIdx.x;
    const int C = (N_NODES + 1023) / 1024;   // 49
    int base = t * C;
    int s = 0;
    for (int i = 0; i < C; ++i) {
        int idx = base + i;
        if (idx < N_NODES) s += deg[idx];
    }
    ps[t] = s;
    __syncthreads();
    for (int off = 1; off < 1024; off <<= 1) {
        int v = 0;
        if (t >= off) v = ps[t - off];
        __syncthreads();
        if (t >= off) ps[t] += v;
        __syncthreads();
    }
    int run = (t > 0) ? ps[t - 1] : 0;
    for (int i = 0; i < C; ++i) {
        int idx = base + i;
        if (idx < N_NODES) {
            cursor[idx] = run;
            run += deg[idx];
        }
    }
}

__global__ void __launch_bounds__(256) k_scatter(const int* __restrict__ dstI,
                                                 int* __restrict__ cursor,
                                                 int* __restrict__ perm,
                                                 int* __restrict__ dstS) {
    int e = blockIdx.x * 256 + threadIdx.x;
    if (e >= N_EDGES) return;
    int d = dstI[e];
    int p = atomicAdd(&cursor[d], 1);
    perm[p] = e;
    dstS[p] = d;
}

// ---------------------------------------------------------------------------
// Atom embedding: h = x @ W_emb + b_emb  (50000x92 @ 92x128)
// ---------------------------------------------------------------------------
__global__ void __launch_bounds__(128) k_embed(const float* __restrict__ x,
                                               const float* __restrict__ W,
                                               const float* __restrict__ b,
                                               float* __restrict__ h,
                                               __bf16* __restrict__ hb) {
    __shared__ float Wl[IN_DIM * NF];
    __shared__ float xs[4][IN_DIM];
    int tid = threadIdx.x;
    for (int i = tid; i < IN_DIM * NF; i += 128) Wl[i] = W[i];
    float bias = b[tid];
    int node0 = blockIdx.x * 64;
    for (int gq = 0; gq < 16; ++gq) {
        int nb = node0 + gq * 4;
        __syncthreads();
        for (int i = tid; i < 4 * IN_DIM; i += 128) {
            int r = i / IN_DIM, k = i - r * IN_DIM;
            int n = nb + r;
            xs[r][k] = (n < N_NODES) ? x[(size_t)n * IN_DIM + k] : 0.0f;
        }
        __syncthreads();
        float a0 = bias, a1 = bias, a2 = bias, a3 = bias;
        #pragma unroll
        for (int k = 0; k < IN_DIM; ++k) {
            float w = Wl[k * NF + tid];
            a0 += xs[0][k] * w; a1 += xs[1][k] * w;
            a2 += xs[2][k] * w; a3 += xs[3][k] * w;
        }
        float accs[4] = {a0, a1, a2, a3};
        #pragma unroll
        for (int r = 0; r < 4; ++r) {
            int n = nb + r;
            if (n < N_NODES) {
                h[(size_t)n * NF + tid]  = accs[r];
                hb[(size_t)n * NF + tid] = (__bf16)accs[r];
            }
        }
    }
}

// ---------------------------------------------------------------------------
// Edge features: RBF(1/d) -> 64 ->silu-> 64  |  sh(9) -> 32 ->silu-> 64
// ---------------------------------------------------------------------------
__global__ void __launch_bounds__(256) k_edge(const float* __restrict__ sh,
    const float* __restrict__ dist,
    const float* __restrict__ shW1, const float* __restrict__ shB1,
    const float* __restrict__ shW2, const float* __restrict__ shB2,
    const float* __restrict__ rbW1, const float* __restrict__ rbB1,
    const float* __restrict__ rbW2, const float* __restrict__ rbB2,
    __bf16* __restrict__ eattr) {
    __shared__ float wf[10752];
    int tid = threadIdx.x;
    for (int i = tid; i < 288;  i += 256) wf[i]         = shW1[i];
    for (int i = tid; i < 32;   i += 256) wf[288 + i]   = shB1[i];
    for (int i = tid; i < 2048; i += 256) wf[320 + i]   = shW2[i];
    for (int i = tid; i < 64;   i += 256) wf[2368 + i]  = shB2[i];
    for (int i = tid; i < 4096; i += 256) wf[2432 + i]  = rbW1[i];
    for (int i = tid; i < 64;   i += 256) wf[6528 + i]  = rbB1[i];
    for (int i = tid; i < 4096; i += 256) wf[6592 + i]  = rbW2[i];
    for (int i = tid; i < 64;   i += 256) wf[10688 + i] = rbB2[i];
    __syncthreads();
    int e = blockIdx.x * 256 + tid;
    if (e >= N_EDGES) return;

    const float* W1 = wf + 2432; const float* B1 = wf + 6528;
    const float* W2 = wf + 6592; const float* B2 = wf + 10688;
    float invd = 1.0f / dist[e];
    const float step = (1.4f - 0.125f) / 63.0f;
    const float gam = 1.0f / (step * step);
    float hid[64];
    #pragma unroll
    for (int j = 0; j < 64; ++j) hid[j] = B1[j];
    for (int i = 0; i < 64; ++i) {
        float c = 0.125f + i * step;
        float d = invd - c;
        float r = __expf(-gam * d * d);
        #pragma unroll
        for (int j = 0; j < 64; ++j) hid[j] += r * W1[i * 64 + j];
    }
    #pragma unroll
    for (int j = 0; j < 64; ++j) hid[j] = siluf_(hid[j]);
    float outv[64];
    #pragma unroll
    for (int o = 0; o < 64; ++o) outv[o] = B2[o];
    for (int j = 0; j < 64; ++j) {
        float hj = hid[j];
        #pragma unroll
        for (int o = 0; o < 64; ++o) outv[o] += hj * W2[j * 64 + o];
    }
    #pragma unroll
    for (int o8 = 0; o8 < 8; ++o8) {
        bf16x8 v;
        #pragma unroll
        for (int j = 0; j < 8; ++j) v[j] = (__bf16)outv[o8 * 8 + j];
        *(bf16x8*)(eattr + (size_t)e * NF + o8 * 8) = v;
    }
    float shv[9];
    #pragma unroll
    for (int i = 0; i < 9; ++i) shv[i] = sh[(size_t)e * 9 + i];
    const float* sW1 = wf;       const float* sB1 = wf + 288;
    const float* sW2 = wf + 320; const float* sB2 = wf + 2368;
    float h2[32];
    #pragma unroll
    for (int j = 0; j < 32; ++j) h2[j] = sB1[j];
    #pragma unroll
    for (int i = 0; i < 9; ++i) {
        float si = shv[i];
        #pragma unroll
        for (int j = 0; j < 32; ++j) h2[j] += si * sW1[i * 32 + j];
    }
    #pragma unroll
    for (int j = 0; j < 32; ++j) h2[j] = siluf_(h2[j]);
    float o2[64];
    #pragma unroll
    for (int o = 0; o < 64; ++o) o2[o] = sB2[o];
    for (int j = 0; j < 32; ++j) {
        float hj = h2[j];
        #pragma unroll
        for (int o = 0; o < 64; ++o) o2[o] += hj * sW2[j * 64 + o];
    }
    #pragma unroll
    for (int o8 = 0; o8 < 8; ++o8) {
        bf16x8 v;
        #pragma unroll
        for (int j = 0; j < 8; ++j) v[j] = (__bf16)o2[o8 * 8 + j];
        *(bf16x8*)(eattr + (size_t)e * NF + 64 + o8 * 8) = v;
    }
}

// ---------------------------------------------------------------------------
// Message layer over dst-sorted edges. Block = 256 sorted edges (contiguous
// dst range). GEMM z=[h_dst|h_src|e] @ {Wg,Wc}, gate, then LDS segment-sum:
// interior nodes -> plain store, boundary nodes -> global atomicAdd.
// ---------------------------------------------------------------------------
__global__ void __launch_bounds__(512) k_msg(
    const __bf16* __restrict__ hb, const __bf16* __restrict__ eattr,
    const int* __restrict__ srcI, const int* __restrict__ perm,
    const int* __restrict__ dstS,
    const __bf16* __restrict__ Wt, const float* __restrict__ bgl,
    const float* __restrict__ bcl, float* __restrict__ agg, int layer)
{
    __shared__ __align__(16) __bf16 lsB[2][2][4096]; // 32 KB weight dbuf
    __shared__ float aggL[SPAN_CAP * NF];            // 32 KB segment accum
    int tid = threadIdx.x;
    int lane = tid & 63, wid = tid >> 6;
    int e0 = blockIdx.x * 256 + wid * 32;
    int rA  = lane & 15;
    int sub = lane >> 4;
    int ko  = sub * 8;
    int eA = e0 + rA, eB = e0 + 16 + rA;
    int eAc = min(eA, N_EDGES - 1), eBc = min(eB, N_EDGES - 1);
    int pe0 = perm[eAc], pe1 = perm[eBc];
    const __bf16* pD0 = hb + (size_t)dstS[eAc] * NF + ko;
    const __bf16* pD1 = hb + (size_t)dstS[eBc] * NF + ko;
    const __bf16* pS0 = hb + (size_t)srcI[pe0] * NF + ko;
    const __bf16* pS1 = hb + (size_t)srcI[pe1] * NF + ko;
    const __bf16* pE0 = eattr + (size_t)pe0 * NF + ko;
    const __bf16* pE1 = eattr + (size_t)pe1 * NF + ko;

    const uint4* gW0 = (const uint4*)(Wt + (size_t)(layer * 2 + 0) * 49152);
    const uint4* gW1 = (const uint4*)(Wt + (size_t)(layer * 2 + 1) * 49152);

    // chunk dst-range (uniform across block)
    int cfirst = blockIdx.x * 256;
    int clast  = min(cfirst + 255, N_EDGES - 1);
    int n0 = dstS[cfirst], n1 = dstS[clast];
    int span = n1 - n0 + 1;
    bool ldsPath = (span <= SPAN_CAP);

    f32x4 accG[2][8], accC[2][8];
    f32x4 zz = {0.f, 0.f, 0.f, 0.f};
    #pragma unroll
    for (int m = 0; m < 2; ++m)
        #pragma unroll
        for (int t = 0; t < 8; ++t) { accG[m][t] = zz; accC[m][t] = zz; }

    // zero segment accumulator + stage weight step 0
    if (ldsPath)
        for (int i = tid; i < SPAN_CAP * NF; i += 512) aggL[i] = 0.0f;
    {
        uint4 r0 = gW0[tid], r1 = gW1[tid];
        ((uint4*)&lsB[0][0][0])[tid] = r0;
        ((uint4*)&lsB[0][1][0])[tid] = r1;
    }
    bf16x8 a0 = *(const bf16x8*)pD0;
    bf16x8 a1 = *(const bf16x8*)pD1;
    __syncthreads();

    for (int s = 0; s < 12; ++s) {
        int cur = s & 1, nxt = cur ^ 1;
        bool more = (s < 11);
        uint4 r0, r1;
        bf16x8 na0, na1;
        if (more) {
            r0 = gW0[(s + 1) * 512 + tid];
            r1 = gW1[(s + 1) * 512 + tid];
            int sn = s + 1;
            const __bf16* b0 = (sn < 4) ? pD0 : (sn < 8) ? pS0 : pE0;
            const __bf16* b1 = (sn < 4) ? pD1 : (sn < 8) ? pS1 : pE1;
            int koff = (sn & 3) * 32;
            na0 = *(const bf16x8*)(b0 + koff);
            na1 = *(const bf16x8*)(b1 + koff);
        }
        #pragma unroll
        for (int t = 0; t < 8; ++t) {
            int n = t * 16 + rA;
            int gran = n * 4 + ((sub + (n >> 1)) & 3);
            bf16x8 bgf = *(const bf16x8*)(&lsB[cur][0][gran * 8]);
            bf16x8 bcf = *(const bf16x8*)(&lsB[cur][1][gran * 8]);
            accG[0][t] = __builtin_amdgcn_mfma_f32_16x16x32_bf16(a0, bgf, accG[0][t], 0, 0, 0);
            accG[1][t] = __builtin_amdgcn_mfma_f32_16x16x32_bf16(a1, bgf, accG[1][t], 0, 0, 0);
            accC[0][t] = __builtin_amdgcn_mfma_f32_16x16x32_bf16(a0, bcf, accC[0][t], 0, 0, 0);
            accC[1][t] = __builtin_amdgcn_mfma_f32_16x16x32_bf16(a1, bcf, accC[1][t], 0, 0, 0);
        }
        if (more) {
            ((uint4*)&lsB[nxt][0][0])[tid] = r0;
            ((uint4*)&lsB[nxt][1][0])[tid] = r1;
            a0 = na0; a1 = na1;
        }
        __syncthreads();
    }

    // epilogue: gate + segment aggregation
    int rowbase = sub * 4;
    int dstv[2][4]; bool valid[2][4];
    #pragma unroll
    for (int m = 0; m < 2; ++m)
        #pragma unroll
        for (int r = 0; r < 4; ++r) {
            int e = e0 + m * 16 + rowbase + r;
            valid[m][r] = (e < N_EDGES);
            dstv[m][r] = dstS[min(e, N_EDGES - 1)];
        }

    if (ldsPath) {
        #pragma unroll
        for (int t = 0; t < 8; ++t) {
            int n = t * 16 + rA;
            float bgn = bgl[n], bcn = bcl[n];
            #pragma unroll
            for (int m = 0; m < 2; ++m) {
                #pragma unroll
                for (int r = 0; r < 4; ++r) {
                    if (valid[m][r]) {
                        float gv = accG[m][t][r] + bgn;
                        float cv = accC[m][t][r] + bcn;
                        float mv = sigmoidf_(gv) * softplusf_(cv);
                        atomicAdd(&aggL[(dstv[m][r] - n0) * NF + n], mv);
                    }
                }
            }
        }
        __syncthreads();
        int total = span * NF;
        for (int idx = tid; idx < total; idx += 512) {
            int ln = idx >> 7, n = idx & 127;
            float v = aggL[idx];
            int d = n0 + ln;
            if (ln == 0 || ln == span - 1)
                atomicAdd(&agg[(size_t)d * NF + n], v);
            else
                agg[(size_t)d * NF + n] = v;   // interior node: exclusive to block
        }
    } else {
        // rare fallback: sparse chunk spanning > SPAN_CAP nodes
        #pragma unroll
        for (int t = 0; t < 8; ++t) {
            int n = t * 16 + rA;
            float bgn = bgl[n], bcn = bcl[n];
            #pragma unroll
            for (int m = 0; m < 2; ++m) {
                #pragma unroll
                for (int r = 0; r < 4; ++r) {
                    if (valid[m][r]) {
                        float gv = accG[m][t][r] + bgn;
                        float cv = accC[m][t][r] + bcn;
                        float mv = sigmoidf_(gv) * softplusf_(cv);
                        atomicAdd(&agg[(size_t)dstv[m][r] * NF + n], mv);
                    }
                }
            }
        }
    }
}

// ---------------------------------------------------------------------------
// h += agg; hb = bf16(h); agg = 0
// ---------------------------------------------------------------------------
__global__ void __launch_bounds__(256) k_update(float* __restrict__ h,
                                                float* __restrict__ agg,
                                                __bf16* __restrict__ hb) {
    size_t i = (size_t)blockIdx.x * 256 + threadIdx.x;
    float4 hv = ((float4*)h)[i];
    float4 av = ((float4*)agg)[i];
    hv.x += av.x; hv.y += av.y; hv.z += av.z; hv.w += av.w;
    ((float4*)h)[i] = hv;
    ((float4*)agg)[i] = make_float4(0.f, 0.f, 0.f, 0.f);
    bf16x4 o;
    o[0] = (__bf16)hv.x; o[1] = (__bf16)hv.y; o[2] = (__bf16)hv.z; o[3] = (__bf16)hv.w;
    *(bf16x4*)(hb + i * 4) = o;
}

// ---------------------------------------------------------------------------
// Readout: per-graph mean (batch sorted -> binary search), fc 128->128->1
// ---------------------------------------------------------------------------
__global__ void __launch_bounds__(128) k_readout(const float* __restrict__ h,
    const int* __restrict__ batch, const float* __restrict__ W1,
    const float* __restrict__ b1, const float* __restrict__ W2,
    const float* __restrict__ b2, float* __restrict__ out) {
    int g = blockIdx.x, tid = threadIdx.x;
    __shared__ int se[2];
    __shared__ float pl[NF];
    __shared__ float red[2];
    if (tid < 2) {
        int target = g + tid;
        int lo = 0, hi = N_NODES;
        while (lo < hi) { int mid = (lo + hi) >> 1; if (batch[mid] < target) lo = mid + 1; else hi = mid; }
        se[tid] = lo;
    }
    __syncthreads();
    int s = se[0], e = se[1];
    float sum = 0.0f;
    for (int n = s; n < e; ++n) sum += h[(size_t)n * NF + tid];
    float cnt = (float)max(e - s, 1);
    pl[tid] = sum / cnt;
    __syncthreads();
    float acc = b1[tid];
    for (int c = 0; c < NF; ++c) acc += pl[c] * W1[c * NF + tid];
    float hid = siluf_(acc);
    float v = hid * W2[tid];
    #pragma unroll
    for (int off = 32; off > 0; off >>= 1) v += __shfl_down(v, off);
    if ((tid & 63) == 0) red[tid >> 6] = v;
    __syncthreads();
    if (tid == 0) out[g] = red[0] + red[1] + b2[0];
}

// ---------------------------------------------------------------------------
extern "C" void kernel_launch(void* const* d_in, const int* in_sizes, int n_in,
                              void* d_out, int out_size, void* d_ws, size_t ws_size,
                              hipStream_t stream) {
    const float* x     = (const float*)d_in[0];
    const int*   eidx  = (const int*)d_in[1];
    const float* sh    = (const float*)d_in[2];
    const float* edist = (const float*)d_in[3];
    const int*   batch = (const int*)d_in[4];
    const float* W_emb = (const float*)d_in[5];
    const float* b_emb = (const float*)d_in[6];
    const float* shW1  = (const float*)d_in[7];
    const float* shB1  = (const float*)d_in[8];
    const float* shW2  = (const float*)d_in[9];
    const float* shB2  = (const float*)d_in[10];
    const float* rbW1  = (const float*)d_in[11];
    const float* rbB1  = (const float*)d_in[12];
    const float* rbW2  = (const float*)d_in[13];
    const float* rbB2  = (const float*)d_in[14];
    const float* Wg    = (const float*)d_in[15];
    const float* bg    = (const float*)d_in[16];
    const float* Wc    = (const float*)d_in[17];
    const float* bc    = (const float*)d_in[18];
    const float* fcW1  = (const float*)d_in[19];
    const float* fcb1  = (const float*)d_in[20];
    const float* fcW2  = (const float*)d_in[21];
    const float* fcb2  = (const float*)d_in[22];
    const int* srcI = eidx;
    const int* dstI = eidx + N_EDGES;

    char* ws = (char*)d_ws;
    float*  h    = (float*)(ws + 0);            // 25,600,000 B
    __bf16* hb   = (__bf16*)(ws + 25600000);    // 12,800,000 B
    float*  agg  = (float*)(ws + 38400000);     // 25,600,000 B
    __bf16* ea   = (__bf16*)(ws + 64000000);    // 128,000,000 B
    __bf16* Wt   = (__bf16*)(ws + 192000000);   //    983,040 B
    int*    deg  = (int*)(ws + 193000000);      //    200,000 B
    int*    curs = (int*)(ws + 193200000);      //    200,000 B
    int*    perm = (int*)(ws + 193400000);      //  2,000,000 B
    int*    dstS = (int*)(ws + 195400000);      //  2,000,000 B

    hipMemsetAsync(agg, 0, (size_t)N_NODES * NF * sizeof(float), stream);
    hipMemsetAsync(deg, 0, (size_t)N_NODES * sizeof(int), stream);
    k_prep_w<<<1920, 256, 0, stream>>>(Wg, Wc, Wt);
    k_embed<<<(N_NODES + 63) / 64, 128, 0, stream>>>(x, W_emb, b_emb, h, hb);
    k_edge<<<(N_EDGES + 255) / 256, 256, 0, stream>>>(sh, edist, shW1, shB1, shW2, shB2,
                                                      rbW1, rbB1, rbW2, rbB2, ea);
    k_deg<<<(N_EDGES + 255) / 256, 256, 0, stream>>>(dstI, deg);
    k_scan<<<1, 1024, 0, stream>>>(deg, curs);
    k_scatter<<<(N_EDGES + 255) / 256, 256, 0, stream>>>(dstI, curs, perm, dstS);
    for (int l = 0; l < N_LAYERS; ++l) {
        k_msg<<<(N_EDGES + 255) / 256, 512, 0, stream>>>(hb, ea, srcI, perm, dstS, Wt,
                                                         bg + l * NF, bc + l * NF, agg, l);
        k_update<<<(N_NODES * NF / 4 + 255) / 256, 256, 0, stream>>>(h, agg, hb);
    }
    k_readout<<<N_GRAPHS, 128, 0, stream>>>(h, batch, fcW1, fcb1, fcW2, fcb2, (float*)d_out);
}

// Round 4
// 1389.716 us; speedup vs baseline: 2.1450x; 2.1450x over previous
//
#include <hip/hip_runtime.h>

typedef __bf16 bf16x8 __attribute__((ext_vector_type(8)));
typedef __bf16 bf16x4 __attribute__((ext_vector_type(4)));
typedef float  f32x4  __attribute__((ext_vector_type(4)));
typedef float  f32x2  __attribute__((ext_vector_type(2)));

#define N_NODES  50000
#define N_EDGES  500000
#define N_GRAPHS 1024
#define NF       128
#define IN_DIM   92
#define N_LAYERS 5
#define SPANMAX  192

__device__ __forceinline__ float sigmoidf_(float x) { return 1.0f / (1.0f + __expf(-x)); }
__device__ __forceinline__ float softplusf_(float x) {
    return fmaxf(x, 0.0f) + __logf(1.0f + __expf(-fabsf(x)));
}
__device__ __forceinline__ float siluf_(float x) { return x * sigmoidf_(x); }

// ---------------------------------------------------------------------------
// Weight prep.
// WeT: per (layer l, gate g): A-frags of We^T (A[m][k] = W[256+k][m]), m,k in [0,128).
//      frag id = ((l*2+g)*8 + mtile)*4 + kstep; frag = 64 lanes x 16B (lane=sub*16+mm).
// WnT: per layer: A-frags of Wn^T, cols F: [0,128)=Wg[k][F], [128,256)=Wc[k][F-128],
//      [256,384)=Wg[128+k][F-256], [384,512)=Wc[128+k][F-384]. frag id=(l*32+mtile)*4+ks.
// ---------------------------------------------------------------------------
__global__ void __launch_bounds__(256) k_prep_w(const float* __restrict__ Wg,
                                                const float* __restrict__ Wc,
                                                __bf16* __restrict__ WeT,
                                                __bf16* __restrict__ WnT) {
    int t = blockIdx.x * 256 + threadIdx.x;
    if (t >= (320 + 640) * 64) return;
    int frag = t >> 6, lane = t & 63;
    int sub = lane >> 4, mm = lane & 15;
    bf16x8 v;
    if (frag < 320) {
        int l = frag / 64; int r = frag % 64;
        int g = r >> 5; int m = (r >> 2) & 7; int ks = r & 3;
        const float* W = g ? Wc : Wg;
        #pragma unroll
        for (int j = 0; j < 8; ++j) {
            int k = ks * 32 + sub * 8 + j;
            v[j] = (__bf16)W[(size_t)l * 384 * 128 + (size_t)(256 + k) * 128 + m * 16 + mm];
        }
        *(bf16x8*)(WeT + (size_t)frag * 512 + lane * 8) = v;
    } else {
        int f2 = frag - 320;
        int l = f2 / 128; int r = f2 % 128;
        int m = r >> 2; int ks = r & 3;
        int F = m * 16 + mm;
        #pragma unroll
        for (int j = 0; j < 8; ++j) {
            int k = ks * 32 + sub * 8 + j;
            float val;
            if      (F < 128) val = Wg[(size_t)l*384*128 + (size_t)k*128 + F];
            else if (F < 256) val = Wc[(size_t)l*384*128 + (size_t)k*128 + (F-128)];
            else if (F < 384) val = Wg[(size_t)l*384*128 + (size_t)(128+k)*128 + (F-256)];
            else              val = Wc[(size_t)l*384*128 + (size_t)(128+k)*128 + (F-384)];
            v[j] = (__bf16)val;
        }
        *(bf16x8*)(WnT + (size_t)f2 * 512 + lane * 8) = v;
    }
}

// ---------------------------------------------------------------------------
// CSR build
// ---------------------------------------------------------------------------
__global__ void __launch_bounds__(256) k_deg(const int* __restrict__ dstI,
                                             int* __restrict__ deg) {
    int e = blockIdx.x * 256 + threadIdx.x;
    if (e < N_EDGES) atomicAdd(&deg[dstI[e]], 1);
}

__global__ void __launch_bounds__(1024) k_scan(const int* __restrict__ deg,
                                               int* __restrict__ cursor) {
    __shared__ int ps[1024];
    int t = threadIdx.x;
    const int C = (N_NODES + 1023) / 1024;
    int base = t * C;
    int s = 0;
    for (int i = 0; i < C; ++i) { int idx = base + i; if (idx < N_NODES) s += deg[idx]; }
    ps[t] = s;
    __syncthreads();
    for (int off = 1; off < 1024; off <<= 1) {
        int v = 0;
        if (t >= off) v = ps[t - off];
        __syncthreads();
        if (t >= off) ps[t] += v;
        __syncthreads();
    }
    int run = (t > 0) ? ps[t - 1] : 0;
    for (int i = 0; i < C; ++i) {
        int idx = base + i;
        if (idx < N_NODES) { cursor[idx] = run; run += deg[idx]; }
    }
}

__global__ void __launch_bounds__(256) k_scatter(const int* __restrict__ srcI,
                                                 const int* __restrict__ dstI,
                                                 int* __restrict__ cursor,
                                                 int* __restrict__ perm,
                                                 int* __restrict__ dstS,
                                                 int* __restrict__ srcS) {
    int e = blockIdx.x * 256 + threadIdx.x;
    if (e >= N_EDGES) return;
    int d = dstI[e];
    int p = atomicAdd(&cursor[d], 1);
    perm[p] = e;
    dstS[p] = d;
    srcS[p] = srcI[e];
}

// ---------------------------------------------------------------------------
// Atom embedding: h = x @ W_emb + b_emb
// ---------------------------------------------------------------------------
__global__ void __launch_bounds__(128) k_embed(const float* __restrict__ x,
                                               const float* __restrict__ W,
                                               const float* __restrict__ b,
                                               float* __restrict__ h,
                                               __bf16* __restrict__ hb) {
    __shared__ float Wl[IN_DIM * NF];
    __shared__ float xs[4][IN_DIM];
    int tid = threadIdx.x;
    for (int i = tid; i < IN_DIM * NF; i += 128) Wl[i] = W[i];
    float bias = b[tid];
    int node0 = blockIdx.x * 64;
    for (int gq = 0; gq < 16; ++gq) {
        int nb = node0 + gq * 4;
        __syncthreads();
        for (int i = tid; i < 4 * IN_DIM; i += 128) {
            int r = i / IN_DIM, k = i - r * IN_DIM;
            int n = nb + r;
            xs[r][k] = (n < N_NODES) ? x[(size_t)n * IN_DIM + k] : 0.0f;
        }
        __syncthreads();
        float a0 = bias, a1 = bias, a2 = bias, a3 = bias;
        #pragma unroll
        for (int k = 0; k < IN_DIM; ++k) {
            float w = Wl[k * NF + tid];
            a0 += xs[0][k] * w; a1 += xs[1][k] * w;
            a2 += xs[2][k] * w; a3 += xs[3][k] * w;
        }
        float accs[4] = {a0, a1, a2, a3};
        #pragma unroll
        for (int r = 0; r < 4; ++r) {
            int n = nb + r;
            if (n < N_NODES) {
                h[(size_t)n * NF + tid]  = accs[r];
                hb[(size_t)n * NF + tid] = (__bf16)accs[r];
            }
        }
    }
}

// ---------------------------------------------------------------------------
// Edge features in DST-SORTED order, 16B XOR-swizzled rows
// ---------------------------------------------------------------------------
__global__ void __launch_bounds__(256) k_edge(const float* __restrict__ sh,
    const float* __restrict__ dist, const int* __restrict__ perm,
    const float* __restrict__ shW1, const float* __restrict__ shB1,
    const float* __restrict__ shW2, const float* __restrict__ shB2,
    const float* __restrict__ rbW1, const float* __restrict__ rbB1,
    const float* __restrict__ rbW2, const float* __restrict__ rbB2,
    char* __restrict__ ea_s) {
    __shared__ float wf[10752];
    int tid = threadIdx.x;
    for (int i = tid; i < 288;  i += 256) wf[i]         = shW1[i];
    for (int i = tid; i < 32;   i += 256) wf[288 + i]   = shB1[i];
    for (int i = tid; i < 2048; i += 256) wf[320 + i]   = shW2[i];
    for (int i = tid; i < 64;   i += 256) wf[2368 + i]  = shB2[i];
    for (int i = tid; i < 4096; i += 256) wf[2432 + i]  = rbW1[i];
    for (int i = tid; i < 64;   i += 256) wf[6528 + i]  = rbB1[i];
    for (int i = tid; i < 4096; i += 256) wf[6592 + i]  = rbW2[i];
    for (int i = tid; i < 64;   i += 256) wf[10688 + i] = rbB2[i];
    __syncthreads();
    int p = blockIdx.x * 256 + tid;
    if (p >= N_EDGES) return;
    int e = perm[p];

    const float* W1 = wf + 2432; const float* B1 = wf + 6528;
    const float* W2 = wf + 6592; const float* B2 = wf + 10688;
    float invd = 1.0f / dist[e];
    const float step = (1.4f - 0.125f) / 63.0f;
    const float gam = 1.0f / (step * step);
    float hid[64];
    #pragma unroll
    for (int j = 0; j < 64; ++j) hid[j] = B1[j];
    for (int i = 0; i < 64; ++i) {
        float c = 0.125f + i * step;
        float d = invd - c;
        float r = __expf(-gam * d * d);
        #pragma unroll
        for (int j = 0; j < 64; ++j) hid[j] += r * W1[i * 64 + j];
    }
    #pragma unroll
    for (int j = 0; j < 64; ++j) hid[j] = siluf_(hid[j]);
    float outv[64];
    #pragma unroll
    for (int o = 0; o < 64; ++o) outv[o] = B2[o];
    for (int j = 0; j < 64; ++j) {
        float hj = hid[j];
        #pragma unroll
        for (int o = 0; o < 64; ++o) outv[o] += hj * W2[j * 64 + o];
    }
    char* rowp = ea_s + (size_t)p * 256;
    int sw = (p & 7) << 4;
    #pragma unroll
    for (int o8 = 0; o8 < 8; ++o8) {
        bf16x8 v;
        #pragma unroll
        for (int j = 0; j < 8; ++j) v[j] = (__bf16)outv[o8 * 8 + j];
        *(bf16x8*)(rowp + ((o8 * 16) ^ sw)) = v;
    }
    float shv[9];
    #pragma unroll
    for (int i = 0; i < 9; ++i) shv[i] = sh[(size_t)e * 9 + i];
    const float* sW1 = wf;       const float* sB1 = wf + 288;
    const float* sW2 = wf + 320; const float* sB2 = wf + 2368;
    float h2[32];
    #pragma unroll
    for (int j = 0; j < 32; ++j) h2[j] = sB1[j];
    #pragma unroll
    for (int i = 0; i < 9; ++i) {
        float si = shv[i];
        #pragma unroll
        for (int j = 0; j < 32; ++j) h2[j] += si * sW1[i * 32 + j];
    }
    #pragma unroll
    for (int j = 0; j < 32; ++j) h2[j] = siluf_(h2[j]);
    float o2[64];
    #pragma unroll
    for (int o = 0; o < 64; ++o) o2[o] = sB2[o];
    for (int j = 0; j < 32; ++j) {
        float hj = h2[j];
        #pragma unroll
        for (int o = 0; o < 64; ++o) o2[o] += hj * sW2[j * 64 + o];
    }
    #pragma unroll
    for (int o8 = 0; o8 < 8; ++o8) {
        bf16x8 v;
        #pragma unroll
        for (int j = 0; j < 8; ++j) v[j] = (__bf16)o2[o8 * 8 + j];
        *(bf16x8*)(rowp + (((8 + o8) * 16) ^ sw)) = v;
    }
}

// ---------------------------------------------------------------------------
// Per-node GEMM: NBd[node][256] = [h@Wg_d + bg | h@Wc_d + bc] (TD = f32 or bf16)
//                NBs[node][256] = [h@Wg_s | h@Wc_s]           (bf16)
// ---------------------------------------------------------------------------
template <typename TD>
__global__ void __launch_bounds__(256) k_node(const __bf16* __restrict__ hb,
                                              const __bf16* __restrict__ WnT,
                                              const float* __restrict__ bgl,
                                              const float* __restrict__ bcl,
                                              TD* __restrict__ NBd,
                                              __bf16* __restrict__ NBs, int layer) {
    int tid = threadIdx.x, lane = tid & 63, w = tid >> 6;
    int sub = lane >> 4, rA = lane & 15;
    int node0 = blockIdx.x * 32;
    bf16x8 Bf[2][4];
    #pragma unroll
    for (int nt = 0; nt < 2; ++nt)
        #pragma unroll
        for (int ks = 0; ks < 4; ++ks) {
            int node = min(node0 + nt * 16 + rA, N_NODES - 1);
            Bf[nt][ks] = *(const bf16x8*)(hb + (size_t)node * 128 + ks * 32 + sub * 8);
        }
    const __bf16* Wbase = WnT + (size_t)layer * 128 * 512;
    f32x4 acc[8][2];
    f32x4 zz = {0.f, 0.f, 0.f, 0.f};
    #pragma unroll
    for (int mt = 0; mt < 8; ++mt) { acc[mt][0] = zz; acc[mt][1] = zz; }
    for (int mt = 0; mt < 8; ++mt) {
        int gm = w * 8 + mt;
        bf16x8 Af[4];
        #pragma unroll
        for (int ks = 0; ks < 4; ++ks)
            Af[ks] = *(const bf16x8*)(Wbase + (size_t)(gm * 4 + ks) * 512 + lane * 8);
        #pragma unroll
        for (int nt = 0; nt < 2; ++nt) {
            f32x4 a = acc[mt][nt];
            #pragma unroll
            for (int ks = 0; ks < 4; ++ks)
                a = __builtin_amdgcn_mfma_f32_16x16x32_bf16(Af[ks], Bf[nt][ks], a, 0, 0, 0);
            acc[mt][nt] = a;
        }
    }
    #pragma unroll
    for (int mt = 0; mt < 8; ++mt) {
        int F = (w * 8 + mt) * 16 + sub * 4;
        f32x4 bias = zz;
        if (w == 0)      bias = *(const f32x4*)(bgl + F);
        else if (w == 1) bias = *(const f32x4*)(bcl + (F - 128));
        #pragma unroll
        for (int nt = 0; nt < 2; ++nt) {
            int node = node0 + nt * 16 + rA;
            if (node >= N_NODES) continue;
            f32x4 vv = acc[mt][nt];
            vv[0] += bias[0]; vv[1] += bias[1]; vv[2] += bias[2]; vv[3] += bias[3];
            if (w < 2) {
                if constexpr (sizeof(TD) == 4) {
                    *(f32x4*)(NBd + (size_t)node * 256 + F) = vv;
                } else {
                    bf16x4 bv;
                    bv[0] = (__bf16)vv[0]; bv[1] = (__bf16)vv[1];
                    bv[2] = (__bf16)vv[2]; bv[3] = (__bf16)vv[3];
                    *(bf16x4*)((__bf16*)NBd + (size_t)node * 256 + F) = bv;
                }
            } else {
                bf16x4 bv;
                bv[0] = (__bf16)vv[0]; bv[1] = (__bf16)vv[1];
                bv[2] = (__bf16)vv[2]; bv[3] = (__bf16)vv[3];
                *(bf16x4*)(NBs + (size_t)node * 256 + (F - 256)) = bv;
            }
        }
    }
}

template <typename TD>
__device__ __forceinline__ f32x4 ld_nb4(const TD* p) {
    if constexpr (sizeof(TD) == 4) {
        return *(const f32x4*)p;
    } else {
        bf16x4 t = *(const bf16x4*)p;
        f32x4 r;
        r[0] = (float)t[0]; r[1] = (float)t[1]; r[2] = (float)t[2]; r[3] = (float)t[3];
        return r;
    }
}

// ---------------------------------------------------------------------------
// Message layer, dst-sorted. 512 thr (8 waves) x 64 edges. Weights-stationary
// MFMA (C=[feat][edge]); epilogue adds NBd[dst]+NBs[src], gates, LDS segment-
// sum into h: interior nodes plain RMW (block-exclusive), boundaries atomic.
// ---------------------------------------------------------------------------
template <typename TD>
__global__ void __launch_bounds__(512) k_msg(
    const char* __restrict__ ea_s, const int* __restrict__ dstS,
    const int* __restrict__ srcS, const __bf16* __restrict__ WeT,
    const TD* __restrict__ NBd, const __bf16* __restrict__ NBs,
    float* __restrict__ h, int layer)
{
    __shared__ __align__(16) char eb[16384];       // 64 rows x 256B, swizzled
    __shared__ __align__(16) float mF[64 * 128];   // 32KB messages (swizzled)
    __shared__ int dl[64];
    __shared__ int rs[SPANMAX], re[SPANMAX];
    int tid = threadIdx.x, lane = tid & 63, w = tid >> 6;
    int sub = lane >> 4, rA = lane & 15;
    int e0 = blockIdx.x * 64;
    int nvalid = min(64, N_EDGES - e0);

    {   // stage 16KB of edge rows (pre-swizzled in global -> linear LDS copy)
        const char* srcp = ea_s + (size_t)e0 * 256;
        *(uint4*)(eb + tid * 16)          = *(const uint4*)(srcp + tid * 16);
        *(uint4*)(eb + (512 + tid) * 16)  = *(const uint4*)(srcp + (512 + tid) * 16);
    }
    if (tid < 64) dl[tid] = dstS[e0 + min(tid, nvalid - 1)];
    for (int i = tid; i < SPANMAX; i += 512) { rs[i] = 0; re[i] = 0; }
    // weight A-frags (registers)
    bf16x8 Ag[4], Ac[4];
    {
        const __bf16* bg_ = WeT + (size_t)(((layer * 2 + 0) * 8 + w) * 4) * 512;
        const __bf16* bc_ = WeT + (size_t)(((layer * 2 + 1) * 8 + w) * 4) * 512;
        #pragma unroll
        for (int ks = 0; ks < 4; ++ks) {
            Ag[ks] = *(const bf16x8*)(bg_ + ks * 512 + lane * 8);
            Ac[ks] = *(const bf16x8*)(bc_ + ks * 512 + lane * 8);
        }
    }
    __syncthreads();
    int n0 = dl[0];
    int span = min(dl[63] - n0 + 1, SPANMAX);
    if (tid < 64) {
        int d = min(dl[tid] - n0, SPANMAX - 1);
        if (tid == 0  || dl[tid - 1] != dl[tid]) rs[d] = tid;
        if (tid == 63 || dl[tid + 1] != dl[tid]) re[d] = tid + 1;
    }
    // K-loop: 4 ntiles x 4 ksteps x 2 gates = 32 MFMA
    f32x4 aG[4], aC[4];
    f32x4 zz = {0.f, 0.f, 0.f, 0.f};
    #pragma unroll
    for (int nt = 0; nt < 4; ++nt) { aG[nt] = zz; aC[nt] = zz; }
    #pragma unroll
    for (int nt = 0; nt < 4; ++nt) {
        int row = nt * 16 + rA;
        int swr = (row & 7) << 4;
        #pragma unroll
        for (int ks = 0; ks < 4; ++ks) {
            bf16x8 bf = *(const bf16x8*)(eb + row * 256 + ((ks * 64 + sub * 16) ^ swr));
            aG[nt] = __builtin_amdgcn_mfma_f32_16x16x32_bf16(Ag[ks], bf, aG[nt], 0, 0, 0);
            aC[nt] = __builtin_amdgcn_mfma_f32_16x16x32_bf16(Ac[ks], bf, aC[nt], 0, 0, 0);
        }
    }
    // gate epilogue -> mF
    int F = w * 16 + sub * 4;
    #pragma unroll
    for (int nt = 0; nt < 4; ++nt) {
        int el = nt * 16 + rA;
        bool valid = el < nvalid;
        int ec = e0 + min(el, nvalid - 1);
        int dst = dstS[ec], src = srcS[ec];
        f32x4 gd = ld_nb4(NBd + (size_t)dst * 256 + F);
        f32x4 cd = ld_nb4(NBd + (size_t)dst * 256 + 128 + F);
        f32x4 gs = ld_nb4(NBs + (size_t)src * 256 + F);
        f32x4 cs = ld_nb4(NBs + (size_t)src * 256 + 128 + F);
        f32x4 mv;
        #pragma unroll
        for (int r = 0; r < 4; ++r) {
            float gi = aG[nt][r] + gd[r] + gs[r];
            float ci = aC[nt][r] + cd[r] + cs[r];
            mv[r] = valid ? sigmoidf_(gi) * softplusf_(ci) : 0.0f;
        }
        *(f32x4*)((char*)mF + el * 512 + ((w * 64 + sub * 16) ^ ((el & 7) << 4))) = mv;
    }
    __syncthreads();
    // segment-sum over runs -> h
    int items = span * 64;
    for (int it = tid; it < items; it += 512) {
        int ln = it >> 6, fp = it & 63;
        int rs_ = rs[ln], re_ = re[ln];
        float s0 = 0.f, s1 = 0.f;
        for (int e = rs_; e < re_; ++e) {
            f32x2 v = *(const f32x2*)((char*)mF + e * 512 + ((fp * 8) ^ ((e & 7) << 4)));
            s0 += v[0]; s1 += v[1];
        }
        int node = n0 + ln;
        float* dp = h + (size_t)node * 128 + fp * 2;
        if (ln == 0 || ln == span - 1) { atomicAdd(dp, s0); atomicAdd(dp + 1, s1); }
        else { dp[0] += s0; dp[1] += s1; }   // interior: block-exclusive
    }
}

// ---------------------------------------------------------------------------
// hb = bf16(h)
// ---------------------------------------------------------------------------
__global__ void __launch_bounds__(256) k_cast(const float* __restrict__ h,
                                              __bf16* __restrict__ hb) {
    size_t i = (size_t)blockIdx.x * 256 + threadIdx.x;
    float4 hv = ((const float4*)h)[i];
    bf16x4 o;
    o[0] = (__bf16)hv.x; o[1] = (__bf16)hv.y; o[2] = (__bf16)hv.z; o[3] = (__bf16)hv.w;
    *(bf16x4*)(hb + i * 4) = o;
}

// ---------------------------------------------------------------------------
// Readout
// ---------------------------------------------------------------------------
__global__ void __launch_bounds__(128) k_readout(const float* __restrict__ h,
    const int* __restrict__ batch, const float* __restrict__ W1,
    const float* __restrict__ b1, const float* __restrict__ W2,
    const float* __restrict__ b2, float* __restrict__ out) {
    int g = blockIdx.x, tid = threadIdx.x;
    __shared__ int se[2];
    __shared__ float pl[NF];
    __shared__ float red[2];
    if (tid < 2) {
        int target = g + tid;
        int lo = 0, hi = N_NODES;
        while (lo < hi) { int mid = (lo + hi) >> 1; if (batch[mid] < target) lo = mid + 1; else hi = mid; }
        se[tid] = lo;
    }
    __syncthreads();
    int s = se[0], e = se[1];
    float sum = 0.0f;
    for (int n = s; n < e; ++n) sum += h[(size_t)n * NF + tid];
    float cnt = (float)max(e - s, 1);
    pl[tid] = sum / cnt;
    __syncthreads();
    float acc = b1[tid];
    for (int c = 0; c < NF; ++c) acc += pl[c] * W1[c * NF + tid];
    float hid = siluf_(acc);
    float v = hid * W2[tid];
    #pragma unroll
    for (int off = 32; off > 0; off >>= 1) v += __shfl_down(v, off);
    if ((tid & 63) == 0) red[tid >> 6] = v;
    __syncthreads();
    if (tid == 0) out[g] = red[0] + red[1] + b2[0];
}

// ---------------------------------------------------------------------------
extern "C" void kernel_launch(void* const* d_in, const int* in_sizes, int n_in,
                              void* d_out, int out_size, void* d_ws, size_t ws_size,
                              hipStream_t stream) {
    const float* x     = (const float*)d_in[0];
    const int*   eidx  = (const int*)d_in[1];
    const float* sh    = (const float*)d_in[2];
    const float* edist = (const float*)d_in[3];
    const int*   batch = (const int*)d_in[4];
    const float* W_emb = (const float*)d_in[5];
    const float* b_emb = (const float*)d_in[6];
    const float* shW1  = (const float*)d_in[7];
    const float* shB1  = (const float*)d_in[8];
    const float* shW2  = (const float*)d_in[9];
    const float* shB2  = (const float*)d_in[10];
    const float* rbW1  = (const float*)d_in[11];
    const float* rbB1  = (const float*)d_in[12];
    const float* rbW2  = (const float*)d_in[13];
    const float* rbB2  = (const float*)d_in[14];
    const float* Wg    = (const float*)d_in[15];
    const float* bg    = (const float*)d_in[16];
    const float* Wc    = (const float*)d_in[17];
    const float* bc    = (const float*)d_in[18];
    const float* fcW1  = (const float*)d_in[19];
    const float* fcb1  = (const float*)d_in[20];
    const float* fcW2  = (const float*)d_in[21];
    const float* fcb2  = (const float*)d_in[22];
    const int* srcI = eidx;
    const int* dstI = eidx + N_EDGES;

    char* ws = (char*)d_ws;
    // Layout (fixed part ends at 199,399,424 B):
    float*  h    = (float*)(ws + 0);              // 25,600,000
    __bf16* hb   = (__bf16*)(ws + 25600000);      // 12,800,000
    char*   ea_s = (char*)(ws + 38400000);        // 128,016,384 (incl. pad)
    int*    dstS = (int*)(ws + 166416384);        //  2,000,000
    int*    srcS = (int*)(ws + 168416384);        //  2,000,000
    int*    deg  = (int*)(ws + 170416384);        //    200,000
    int*    curs = (int*)(ws + 170616384);        //    200,000
    int*    perm = (int*)(ws + 170816384);        //  2,000,000
    __bf16* WeT  = (__bf16*)(ws + 172816384);     //    327,680
    __bf16* WnT  = (__bf16*)(ws + 173144064);     //    655,360
    __bf16* NBs  = (__bf16*)(ws + 173799424);     // 25,600,000
    void*   NBd  = (void*)(ws + 199399424);       // 51.2 MB (f32) or 25.6 MB (bf16)
    bool nbf32 = (ws_size >= 250599424ULL);

    hipMemsetAsync(deg, 0, (size_t)N_NODES * sizeof(int), stream);
    k_prep_w<<<240, 256, 0, stream>>>(Wg, Wc, WeT, WnT);
    k_embed<<<(N_NODES + 63) / 64, 128, 0, stream>>>(x, W_emb, b_emb, h, hb);
    k_deg<<<(N_EDGES + 255) / 256, 256, 0, stream>>>(dstI, deg);
    k_scan<<<1, 1024, 0, stream>>>(deg, curs);
    k_scatter<<<(N_EDGES + 255) / 256, 256, 0, stream>>>(srcI, dstI, curs, perm, dstS, srcS);
    k_edge<<<(N_EDGES + 255) / 256, 256, 0, stream>>>(sh, edist, perm, shW1, shB1, shW2, shB2,
                                                      rbW1, rbB1, rbW2, rbB2, ea_s);
    for (int l = 0; l < N_LAYERS; ++l) {
        if (nbf32) {
            k_node<float><<<(N_NODES + 31) / 32, 256, 0, stream>>>(
                hb, WnT, bg + l * NF, bc + l * NF, (float*)NBd, NBs, l);
            k_msg<float><<<(N_EDGES + 63) / 64, 512, 0, stream>>>(
                ea_s, dstS, srcS, WeT, (const float*)NBd, NBs, h, l);
        } else {
            k_node<__bf16><<<(N_NODES + 31) / 32, 256, 0, stream>>>(
                hb, WnT, bg + l * NF, bc + l * NF, (__bf16*)NBd, NBs, l);
            k_msg<__bf16><<<(N_EDGES + 63) / 64, 512, 0, stream>>>(
                ea_s, dstS, srcS, WeT, (const __bf16*)NBd, NBs, h, l);
        }
        if (l < N_LAYERS - 1)
            k_cast<<<(N_NODES * NF / 4) / 256, 256, 0, stream>>>(h, hb);
    }
    k_readout<<<N_GRAPHS, 128, 0, stream>>>(h, batch, fcW1, fcb1, fcW2, fcb2, (float*)d_out);
}